// Round 4
// baseline (22583.681 us; speedup 1.0000x reference)
//
#include <hip/hip_runtime.h>
#include <stdint.h>

typedef unsigned short us;

__device__ __forceinline__ float bf2f(us x) {
    union { unsigned u; float f; } v; v.u = ((unsigned)x) << 16; return v.f;
}
__device__ __forceinline__ us f2bf(float f) {
    union { float f; unsigned u; } v; v.f = f;
    unsigned u = v.u;
    u += 0x7FFFu + ((u >> 16) & 1u);   // RNE
    return (us)(u >> 16);
}
// flag==1: buffer is fp32; flag==0: buffer is bf16
__device__ __forceinline__ float ldin(const void* p, size_t i, int f) {
    return f ? ((const float*)p)[i] : bf2f(((const us*)p)[i]);
}

// ------------------------------------------------------------------
// Dtype probe: bf16 NaN/Inf bit patterns ((u&0x7F80)==0x7F80) cannot occur
// in genuine randn bf16 data, but appear w.p. 2^-8 per halfword when the
// buffer actually holds fp32 (low mantissa halfwords are ~uniform).
// ------------------------------------------------------------------
__global__ void detect_dtype(const us* __restrict__ x, int* __restrict__ flag)
{
    __shared__ int cnt;
    if (threadIdx.x == 0) cnt = 0;
    __syncthreads();
    int c = 0;
    for (int i = threadIdx.x; i < 32768; i += 256) {
        us u = x[i];
        if ((u & 0x7F80u) == 0x7F80u) c++;
    }
    atomicAdd(&cnt, c);
    __syncthreads();
    if (threadIdx.x == 0) *flag = (cnt > 0) ? 1 : 0;
}

// ------------------------------------------------------------------
// qkv = x_chunk @ W_qkv + b_qkv   (one thread per output element, fp32 acc)
// ------------------------------------------------------------------
__global__ __launch_bounds__(256)
void qkv_gemm_f32(const void* __restrict__ x, const void* __restrict__ W,
                  const void* __restrict__ bq, float* __restrict__ qkv,
                  const int* __restrict__ flag, size_t row0, int nrows)
{
    const int f = *flag;
    const size_t tid = (size_t)blockIdx.x * 256 + threadIdx.x;
    if (tid >= (size_t)nrows * 2496) return;
    const int col = (int)(tid % 2496);
    const size_t row = tid / 2496;
    float acc = ldin(bq, col, f);
    if (f) {
        const float* xr = (const float*)x + (row0 + row) * 768;
        const float* Wp = (const float*)W + col;
        for (int k = 0; k < 768; k++) acc += xr[k] * Wp[(size_t)k * 2496];
    } else {
        const us* xr = (const us*)x + (row0 + row) * 768;
        const us* Wp = (const us*)W + col;
        for (int k = 0; k < 768; k++) acc += bf2f(xr[k]) * bf2f(Wp[(size_t)k * 2496]);
    }
    qkv[tid] = acc;
}

// ------------------------------------------------------------------
// r1,r2 = elementwise(z1,z2,v); thread per (bh, n, e)
// ------------------------------------------------------------------
__global__ __launch_bounds__(256)
void zr_kernel(const float* __restrict__ qkv, const void* __restrict__ w1,
               const void* __restrict__ w2, float* __restrict__ r1,
               float* __restrict__ r2, const int* __restrict__ flag, int CB)
{
    const int f = *flag;
    const size_t tid = (size_t)blockIdx.x * 256 + threadIdx.x;
    if (tid >= (size_t)CB * 12 * 1024 * 64) return;
    const int e = (int)(tid & 63);
    const size_t rest = tid >> 6;
    const int n = (int)(rest & 1023);
    const int bh = (int)(rest >> 10);
    const int b = bh / 12, h = bh % 12;
    const float* krow = qkv + ((size_t)b * 1024 + n) * 2496 + 768 + h * 64;
    float z1 = 0.f, z2 = 0.f;
    if (f) {
        const float* w1p = (const float*)w1 + (size_t)h * 4096 + e;
        const float* w2p = (const float*)w2 + (size_t)h * 4096 + e;
        for (int d = 0; d < 64; d++) {
            const float kv = krow[d];
            z1 += kv * w1p[d * 64]; z2 += kv * w2p[d * 64];
        }
    } else {
        const us* w1p = (const us*)w1 + (size_t)h * 4096 + e;
        const us* w2p = (const us*)w2 + (size_t)h * 4096 + e;
        for (int d = 0; d < 64; d++) {
            const float kv = krow[d];
            z1 += kv * bf2f(w1p[d * 64]); z2 += kv * bf2f(w2p[d * 64]);
        }
    }
    const float vv = qkv[((size_t)b * 1024 + n) * 2496 + 1536 + h * 64 + e];
    const float ec = vv * (-1.0f / 3072.0f);   // -v/N * SCALE
    const float sig = 1.f / (1.f + __expf(-z2));
    r1[tid] = ec * z2 * sig;
    r2[tid] = ec * z1 * (sig * (1.f + z2 * (1.f - sig)));
}

// ------------------------------------------------------------------
// g = k^T @ r (accumulated over n), per-e norm, wu = w - g/(||g||+1).
// One block per (b_local, h).
// ------------------------------------------------------------------
__global__ __launch_bounds__(256)
void grad_update(const float* __restrict__ qkv, const float* __restrict__ r1,
                 const float* __restrict__ r2, const void* __restrict__ w1,
                 const void* __restrict__ w2, float* __restrict__ wu1,
                 float* __restrict__ wu2, const int* __restrict__ flag)
{
    const int f = *flag;
    const int bh = blockIdx.x, b = bh / 12, h = bh % 12;
    __shared__ float ks[64][64];      // k chunk [n][d]
    __shared__ float gs[2][64][65];   // g1,g2 [d][e], padded
    __shared__ float inv[2][64];
    const int t = threadIdx.x;
    const int e = t & 63, dq = t >> 6;   // dq in 0..3
    float g1[16], g2[16];
    for (int i = 0; i < 16; i++) { g1[i] = 0.f; g2[i] = 0.f; }
    for (int ch = 0; ch < 16; ch++) {
        const int n0 = ch * 64;
        __syncthreads();
        for (int i = t; i < 4096; i += 256) {
            const int nn = i >> 6, dd = i & 63;
            ks[nn][dd] = qkv[((size_t)b * 1024 + n0 + nn) * 2496 + 768 + h * 64 + dd];
        }
        __syncthreads();
        const float* r1p = r1 + ((size_t)bh * 1024 + n0) * 64 + e;
        const float* r2p = r2 + ((size_t)bh * 1024 + n0) * 64 + e;
        for (int nn = 0; nn < 64; nn++) {
            const float rv1 = r1p[nn * 64], rv2 = r2p[nn * 64];
            for (int i = 0; i < 16; i++) {
                const float kv = ks[nn][dq + i * 4];
                g1[i] += kv * rv1; g2[i] += kv * rv2;
            }
        }
    }
    __syncthreads();
    for (int i = 0; i < 16; i++) { gs[0][dq + i * 4][e] = g1[i]; gs[1][dq + i * 4][e] = g2[i]; }
    __syncthreads();
    if (t < 128) {
        const int w = t >> 6, ee = t & 63;
        float s = 0.f;
        for (int d = 0; d < 64; d++) { const float g = gs[w][d][ee]; s += g * g; }
        inv[w][ee] = 1.f / (sqrtf(s) + 1.f);
    }
    __syncthreads();
    for (int i = t; i < 4096; i += 256) {
        const int d = i >> 6, ee = i & 63;
        const float w1v = ldin(w1, (size_t)h * 4096 + i, f);
        const float w2v = ldin(w2, (size_t)h * 4096 + i, f);
        wu1[(size_t)bh * 4096 + i] = w1v - gs[0][d][ee] * inv[0][ee];
        wu2[(size_t)bh * 4096 + i] = w2v - gs[1][d][ee] * inv[1][ee];
    }
}

// ------------------------------------------------------------------
// x1 = (q@wu1) * silu(q@wu2); thread per (bh, n, e); writes xc[:,0:768]
// ------------------------------------------------------------------
__global__ __launch_bounds__(256)
void x1_kernel(const float* __restrict__ qkv, const float* __restrict__ wu1,
               const float* __restrict__ wu2, float* __restrict__ xc, int CB)
{
    const size_t tid = (size_t)blockIdx.x * 256 + threadIdx.x;
    if (tid >= (size_t)CB * 12 * 1024 * 64) return;
    const int e = (int)(tid & 63);
    const size_t rest = tid >> 6;
    const int n = (int)(rest & 1023);
    const int bh = (int)(rest >> 10);
    const int b = bh / 12, h = bh % 12;
    const float* qrow = qkv + ((size_t)b * 1024 + n) * 2496 + h * 64;
    const float* w1p = wu1 + (size_t)bh * 4096 + e;
    const float* w2p = wu2 + (size_t)bh * 4096 + e;
    float z1 = 0.f, z2 = 0.f;
    for (int d = 0; d < 64; d++) {
        const float qv = qrow[d];
        z1 += qv * w1p[d * 64]; z2 += qv * w2p[d * 64];
    }
    const float sig = 1.f / (1.f + __expf(-z2));
    xc[((size_t)b * 1024 + n) * 832 + h * 64 + e] = z1 * z2 * sig;
}

// ------------------------------------------------------------------
// Depthwise 3x3 branch; one block per (b_local, group of 4 channels).
// ------------------------------------------------------------------
__global__ __launch_bounds__(256)
void dwc_f32(const float* __restrict__ qkv, const void* __restrict__ w3,
             float* __restrict__ xc, const int* __restrict__ flag)
{
    const int f = *flag;
    __shared__ float qch[4][1026], kch[4][1026], vch[4][1026];
    __shared__ float w3s[4][12];
    const int b = blockIdx.x >> 4, dg = blockIdx.x & 15;
    const int t = threadIdx.x;
    for (int rr = 0; rr < 4; rr++) {
        const int n = t + rr * 256;
        const float* rp = qkv + ((size_t)b * 1024 + n) * 2496 + 2304 + dg * 4;
        for (int c = 0; c < 4; c++) {
            qch[c][n] = rp[c]; kch[c][n] = rp[64 + c]; vch[c][n] = rp[128 + c];
        }
    }
    __syncthreads();
    if (t < 128) {
        const int c = t >> 5, x = t & 31;
        float g[9];
        for (int i = 0; i < 9; i++) g[i] = 0.f;
        for (int y = 0; y < 32; y++) {
            const float e = vch[c][y * 32 + x] * (-1.0f / 3072.0f); // -v/(h*w)*SCALE
            for (int dy = -1; dy <= 1; dy++) {
                const int yy = y + dy;
                if (yy < 0 || yy > 31) continue;
                for (int dx = -1; dx <= 1; dx++) {
                    const int xx = x + dx;
                    if (xx < 0 || xx > 31) continue;
                    g[(dy + 1) * 3 + dx + 1] += kch[c][yy * 32 + xx] * e;
                }
            }
        }
        for (int m = 16; m >= 1; m >>= 1)
            for (int i = 0; i < 9; i++)
                g[i] += __shfl_xor(g[i], m, 64);
        if (x == 0) {
            float s = 0.f;
            for (int i = 0; i < 9; i++) s += g[i] * g[i];
            const float nrm = 1.f / (sqrtf(s) + 1.f);
            const int d = dg * 4 + c;
            for (int i = 0; i < 9; i++)
                w3s[c][i] = ldin(w3, (size_t)d * 9 + i, f) - g[i] * nrm;
        }
    }
    __syncthreads();
    for (int rr = 0; rr < 4; rr++) {
        const int n = t + rr * 256;
        const int y = n >> 5, xx = n & 31;
        for (int cc = 0; cc < 4; cc++) {
            float acc = 0.f;
            for (int ky = 0; ky < 3; ky++) {
                const int yy = y + ky - 1;
                if (yy < 0 || yy > 31) continue;
                for (int kx = 0; kx < 3; kx++) {
                    const int xz = xx + kx - 1;
                    if (xz < 0 || xz > 31) continue;
                    acc += qch[cc][yy * 32 + xz] * w3s[cc][ky * 3 + kx];
                }
            }
            xc[((size_t)b * 1024 + n) * 832 + 768 + dg * 4 + cc] = acc;
        }
    }
}

// ------------------------------------------------------------------
// out_chunk = xc @ proj_W + proj_b (flag-aware store)
// ------------------------------------------------------------------
__global__ __launch_bounds__(256)
void proj_gemm_f32(const float* __restrict__ xc, const void* __restrict__ W,
                   const void* __restrict__ pb, void* __restrict__ out,
                   const int* __restrict__ flag, size_t row0, int nrows)
{
    const int f = *flag;
    const size_t tid = (size_t)blockIdx.x * 256 + threadIdx.x;
    if (tid >= (size_t)nrows * 768) return;
    const int col = (int)(tid % 768);
    const size_t row = tid / 768;
    float acc = ldin(pb, col, f);
    const float* xr = xc + row * 832;
    if (f) {
        const float* Wp = (const float*)W + col;
        for (int j = 0; j < 832; j++) acc += xr[j] * Wp[(size_t)j * 768];
        ((float*)out)[(row0 + row) * 768 + col] = acc;
    } else {
        const us* Wp = (const us*)W + col;
        for (int j = 0; j < 832; j++) acc += xr[j] * bf2f(Wp[(size_t)j * 768]);
        ((us*)out)[(row0 + row) * 768 + col] = f2bf(acc);
    }
}

// ------------------------------------------------------------------
// fp32 intermediates in ws, batch-chunked. Per-CB-unit fp32 elems:
//   qkv 1024*2496 + r1/r2 2*12*1024*64 + wu 2*12*4096 + xc 1024*832
//   = 5,079,040 elems = 20.3 MB  (CB=1 min footprint ~20.3 MB + 256 B)
// ------------------------------------------------------------------
extern "C" void kernel_launch(void* const* d_in, const int* in_sizes, int n_in,
                              void* d_out, int out_size, void* d_ws, size_t ws_size,
                              hipStream_t stream) {
    const void* x      = d_in[0];
    const void* W_qkv  = d_in[1];
    const void* b_qkv  = d_in[2];
    const void* w1     = d_in[3];
    const void* w2     = d_in[4];
    const void* w3     = d_in[5];
    const void* proj_W = d_in[6];
    const void* proj_b = d_in[7];

    int* flag = (int*)d_ws;
    float* base = (float*)((char*)d_ws + 256);

    const size_t per = 5079040ULL;  // fp32 elems per CB unit
    int CB = 1;
    for (int cand = 32; cand >= 1; cand >>= 1)
        if (256 + per * cand * 4 <= ws_size) { CB = cand; break; }

    float* qkv_c = base;
    float* r1  = qkv_c + (size_t)CB * 1024 * 2496;
    float* r2  = r1  + (size_t)CB * 12 * 1024 * 64;
    float* wu1 = r2  + (size_t)CB * 12 * 1024 * 64;
    float* wu2 = wu1 + (size_t)CB * 12 * 4096;
    float* xc  = wu2 + (size_t)CB * 12 * 4096;

    detect_dtype<<<1, 256, 0, stream>>>((const us*)x, flag);

    const int passes = 32 / CB;
    const int nrows = CB * 1024;
    for (int p = 0; p < passes; p++) {
        const size_t row0 = (size_t)p * CB * 1024;
        qkv_gemm_f32<<<(int)(((size_t)nrows * 2496 + 255) / 256), 256, 0, stream>>>(
            x, W_qkv, b_qkv, qkv_c, flag, row0, nrows);
        zr_kernel<<<CB * 3072, 256, 0, stream>>>(qkv_c, w1, w2, r1, r2, flag, CB);
        grad_update<<<CB * 12, 256, 0, stream>>>(qkv_c, r1, r2, w1, w2, wu1, wu2, flag);
        x1_kernel<<<CB * 3072, 256, 0, stream>>>(qkv_c, wu1, wu2, xc, CB);
        dwc_f32<<<CB * 16, 256, 0, stream>>>(qkv_c, w3, xc, flag);
        proj_gemm_f32<<<(int)(((size_t)nrows * 768 + 255) / 256), 256, 0, stream>>>(
            xc, proj_W, proj_b, d_out, flag, row0, nrows);
    }
}